// Round 16
// baseline (97.262 us; speedup 1.0000x reference)
//
#include <hip/hip_runtime.h>

// Problem constants (from reference setup_inputs)
static constexpr int B = 32;
static constexpr int P = 19248;
static constexpr int G = 32;
static constexpr int C = 41;          // num classes
static constexpr float POS_TH = 0.5f;
static constexpr float NEG_TH = 0.4f;

static constexpr int TM = 128;                   // block size
static constexpr int PBM = (P + TM - 1) / TM;    // 151 tiles per batch
static constexpr int NPART = 8;                  // match prior partitions
static constexpr int PPART = P / NPART;          // 2406 (exact)
static constexpr int P4 = P / 4;                 // 4812 float4 per batch
static constexpr int NMATCH = B * G * NPART;     // 8192 wave assignments

__device__ __forceinline__ float sl1(float d) {
    d = fabsf(d);
    return d < 1.0f ? 0.5f * d * d : d - 0.5f;
}

__device__ __forceinline__ unsigned long long umax64(unsigned long long a,
                                                     unsigned long long b) {
    return a > b ? a : b;
}

// ---------------------------------------------------------------------------
// Kernel 1 (merged): main streaming + per-wave match side-job.
// KEY ORDERING (vmcnt retires in issue order — m135): all scalar global
// loads (gt, labels, priors[p], loc[p], match gt) are issued BEFORE the 11
// global_load_lds staging issues; the match loop's prior loads also precede
// staging. Between staging-issue and vmcnt(0) there are ZERO global loads
// (pure reg/LDS VALU), so the conf-independent compute genuinely overlaps
// the staging HBM latency. Main phase is UNFORCED (no bp dependency);
// forced-prior corrections are applied exactly in k_topk (R14-proven).
// Match: wave wg = (b*PBM+bx)*2+wid < 8192 owns (b_m, g_m, part).
// ---------------------------------------------------------------------------
__global__ __launch_bounds__(TM) void k_mega(
    const float* __restrict__ loc_data, const float* __restrict__ conf_data,
    const float* __restrict__ priors, const float* __restrict__ gt,
    const int* __restrict__ labels,
    unsigned long long* __restrict__ bp_part,
    float* __restrict__ mined, float4* __restrict__ partial,
    int* __restrict__ done) {
    int bx = blockIdx.x, b = blockIdx.y;
    int tid = threadIdx.x;
    int lane = tid & 63, wid = tid >> 6;
    if (bx == 0 && b == 0 && tid == 0) *done = 0;
    __shared__ float sconf[TM * C];
    __shared__ float4 sg[G];
    __shared__ float sarea[G];
    __shared__ int slab[G];

    int p0 = bx * TM;
    int p = p0 + tid;

    // ---- preloads: EVERYTHING global-scalar, before any staging issue ----
    float4 g4l = make_float4(0, 0, 0, 0);
    int lab = 0;
    if (tid < G) {
        g4l = reinterpret_cast<const float4*>(gt)[b * G + tid];
        lab = labels[b * G + tid];
    }
    float4 pr = make_float4(0, 0, 0, 1.0f), ld4 = make_float4(0, 0, 0, 0);
    if (p < P) {
        pr = reinterpret_cast<const float4*>(priors)[p];
        ld4 = reinterpret_cast<const float4*>(loc_data)[b * P + p];
    }
    int wg = (b * PBM + bx) * 2 + wid;        // 0..9663
    bool mact = (wg < NMATCH);
    float4 gtm = make_float4(0, 0, 0, 0);
    int b_m = 0, g_m = 0, part = 0;
    if (mact) {
        b_m = wg >> 8; g_m = (wg >> 3) & 31; part = wg & 7;
        gtm = reinterpret_cast<const float4*>(gt)[b_m * G + g_m];  // broadcast
    }

    // ---- match side-job (prior loads precede staging -> no vmcnt drain) ----
    if (mact) {
        float ga = (gtm.z - gtm.x) * (gtm.w - gtm.y);
        float best = -1.0f; int bi = 0;
        int pbase = part * PPART;
        for (int i = lane; i < PPART; i += 64) {
            int pp = pbase + i;
            float4 prm = reinterpret_cast<const float4*>(priors)[pp];
            float px1 = prm.x - prm.z * 0.5f, py1 = prm.y - prm.w * 0.5f;
            float px2 = prm.x + prm.z * 0.5f, py2 = prm.y + prm.w * 0.5f;
            float parea = (px2 - px1) * (py2 - py1);
            float lx = fmaxf(gtm.x, px1), ly = fmaxf(gtm.y, py1);
            float rx = fminf(gtm.z, px2), ry = fminf(gtm.w, py2);
            float w = fmaxf(rx - lx, 0.0f), h = fmaxf(ry - ly, 0.0f);
            float inter = w * h;
            float iou = __fdividef(inter, ga + parea - inter);
            if (iou > best) { best = iou; bi = pp; }   // ascending p: first max
        }
        // best >= 0 always: float bits order-preserving
        unsigned long long pk =
            ((unsigned long long)__float_as_uint(best) << 32)
            | (unsigned)(0xFFFFFFFFu - (unsigned)bi);
#pragma unroll
        for (int d = 32; d; d >>= 1) {
            unsigned long long o = __shfl_xor(pk, d);
            if (o > pk) pk = o;
        }
        if (lane == 0) bp_part[(part * B + b_m) * G + g_m] = pk;
    }

    // ---- block-shared tables ----
    if (tid < G) {
        sg[tid] = g4l;
        sarea[tid] = (g4l.z - g4l.x) * (g4l.w - g4l.y);
        slab[tid] = lab;
    }
    __syncthreads();

    // ---- NOW issue conf staging (no global loads after this until wait) ----
    int valid = min(TM, P - p0);
    size_t gbase = ((size_t)b * P + p0) * C;
    int tot4 = (valid * C) >> 2;          // exact: 128*41 and 48*41 both %4==0
    const float4* g4p = reinterpret_cast<const float4*>(conf_data + gbase);
    float4* s4 = reinterpret_cast<float4*>(sconf);
#if defined(__has_builtin) && __has_builtin(__builtin_amdgcn_global_load_lds)
    typedef const __attribute__((address_space(1))) char* gas1_t;
    typedef __attribute__((address_space(3))) char* las3_t;
#define GL(j) { int i = tid + (j) * TM; if (i < tot4) \
    __builtin_amdgcn_global_load_lds((gas1_t)(g4p + i), (las3_t)(s4 + i), 16, 0, 0); }
    GL(0) GL(1) GL(2) GL(3) GL(4) GL(5) GL(6) GL(7) GL(8) GL(9) GL(10)
#undef GL
#define STAGE_WAIT asm volatile("s_waitcnt vmcnt(0)" ::: "memory")
#else
    float4 r0, r1, r2, r3, r4, r5, r6, r7, r8, r9, r10;
#define LD(j, rj) { int i = tid + (j) * TM; if (i < tot4) rj = g4p[i]; }
    LD(0, r0) LD(1, r1) LD(2, r2) LD(3, r3) LD(4, r4) LD(5, r5)
    LD(6, r6) LD(7, r7) LD(8, r8) LD(9, r9) LD(10, r10)
#undef LD
#define STAGE_WAIT do { \
    int i; \
    i = tid + 0*TM;  if (i < tot4) s4[i] = r0; \
    i = tid + 1*TM;  if (i < tot4) s4[i] = r1; \
    i = tid + 2*TM;  if (i < tot4) s4[i] = r2; \
    i = tid + 3*TM;  if (i < tot4) s4[i] = r3; \
    i = tid + 4*TM;  if (i < tot4) s4[i] = r4; \
    i = tid + 5*TM;  if (i < tot4) s4[i] = r5; \
    i = tid + 6*TM;  if (i < tot4) s4[i] = r6; \
    i = tid + 7*TM;  if (i < tot4) s4[i] = r7; \
    i = tid + 8*TM;  if (i < tot4) s4[i] = r8; \
    i = tid + 9*TM;  if (i < tot4) s4[i] = r9; \
    i = tid + 10*TM; if (i < tot4) s4[i] = r10; \
} while (0)
#endif

    // ---- conf-independent compute: pure reg/LDS, overlaps staging ----
    float my_box = 0.0f, my_posc = 0.0f; int my_pos = 0;
    bool pos = false, neutral = false;
    int cls = 0;
    if (p < P) {
        float px1 = pr.x - pr.z * 0.5f, py1 = pr.y - pr.w * 0.5f;
        float px2 = pr.x + pr.z * 0.5f, py2 = pr.y + pr.w * 0.5f;
        float parea = (px2 - px1) * (py2 - py1);
        float ov = -1.0f; int bidx = 0;
#pragma unroll
        for (int g = 0; g < G; ++g) {
            float4 gb = sg[g];
            float lx = fmaxf(gb.x, px1), ly = fmaxf(gb.y, py1);
            float rx = fminf(gb.z, px2), ry = fminf(gb.w, py2);
            float w = fmaxf(rx - lx, 0.0f), h = fmaxf(ry - ly, 0.0f);
            float inter = w * h;
            float iou = __fdividef(inter, sarea[g] + parea - inter);
            if (iou > ov) { ov = iou; bidx = g; }   // strict > keeps FIRST g
        }
        int gidx = 0;
        if (ov >= POS_TH)       { pos = true; gidx = bidx; }
        else if (ov >= NEG_TH)  { neutral = true; }
        if (pos) {
            cls = slab[gidx] + 1;
            float4 gb = sg[gidx];
            float mcx = (gb.x + gb.z) * 0.5f, mcy = (gb.y + gb.w) * 0.5f;
            float tx = (mcx - pr.x) / (0.1f * pr.z);
            float ty = (mcy - pr.y) / (0.1f * pr.w);
            float tw = __logf(fmaxf((gb.z - gb.x) / pr.z, 1e-8f)) / 0.2f;
            float th = __logf(fmaxf((gb.w - gb.y) / pr.w, 1e-8f)) / 0.2f;
            my_box = sl1(ld4.x - tx) + sl1(ld4.y - ty) + sl1(ld4.z - tw) + sl1(ld4.w - th);
        }
        my_pos = pos ? 1 : 0;
    }

    // ---- staging complete -> LSE/CE ----
    STAGE_WAIT;
#undef STAGE_WAIT
    __syncthreads();

    if (p < P) {
        const float* cv = &sconf[tid * C];
        float mx = cv[0];
#pragma unroll
        for (int c = 1; c < C; ++c) mx = fmaxf(mx, cv[c]);
        float se = 0.0f;
#pragma unroll
        for (int c = 0; c < C; ++c) se += __expf(cv[c] - mx);
        float lse = mx + __logf(se);
        float lc = lse - cv[cls];          // >= 0 always
        mined[(size_t)b * P + p] = (pos || neutral) ? 0.0f : lc;
        my_posc = pos ? lc : 0.0f;
    }

#pragma unroll
    for (int d = 32; d; d >>= 1) {
        my_box  += __shfl_xor(my_box, d);
        my_posc += __shfl_xor(my_posc, d);
        my_pos  += __shfl_xor(my_pos, d);
    }
    __shared__ float rb[2], rc[2]; __shared__ int rp[2];
    if (lane == 0) { rb[wid] = my_box; rc[wid] = my_posc; rp[wid] = my_pos; }
    __syncthreads();
    if (tid == 0) {
        partial[b * PBM + bx] =
            make_float4(rb[0] + rb[1], rc[0] + rc[1], (float)(rp[0] + rp[1]), 0.0f);
    }
}

// ---------------------------------------------------------------------------
// k_topk (R14-proven exact): correction preamble + per-batch top-k + final.
// Preamble (tid<32): combine bp parts -> forced prior per g; dedup (later g
// wins); recompute each forced prior's UNFORCED state bit-identically and
// FORCED state; emit deltas; zero mined[p] in-place (block-local read).
// Then 3-level radix select (zero-skip) on corrected mined with corrected k.
// corr[b] = (neg, dbox, dposc, dnp). Last block reduces everything -> out.
// ---------------------------------------------------------------------------
__global__ __launch_bounds__(1024) void k_topk(
    const float* __restrict__ mined, const float4* __restrict__ partial,
    const unsigned long long* __restrict__ bp_part,
    const float* __restrict__ loc_data, const float* __restrict__ conf_data,
    const float* __restrict__ priors, const float* __restrict__ gt,
    const int* __restrict__ labels,
    float* __restrict__ mined_mut,
    float4* __restrict__ corr, int* __restrict__ done,
    float* __restrict__ out) {
    int b = blockIdx.x;
    const float4* mb4 = reinterpret_cast<const float4*>(mined + (size_t)b * P);
    int tid = threadIdx.x;
    int lane = tid & 63, wid = tid >> 6;

    __shared__ float4 sgt[G];
    __shared__ float sga[G];
    __shared__ int sfp[G];
    __shared__ float scorr[3];

    if (tid < G) {
        unsigned long long mx = 0ull;
#pragma unroll
        for (int q = 0; q < NPART; ++q)
            mx = umax64(mx, bp_part[(q * B + b) * G + tid]);
        sfp[tid] = (int)(0xFFFFFFFFu - (unsigned)mx);
        float4 g4 = reinterpret_cast<const float4*>(gt)[b * G + tid];
        sgt[tid] = g4;
        sga[tid] = (g4.z - g4.x) * (g4.w - g4.y);
    }
    __syncthreads();

    float dnp_f = 0.0f, dbox_f = 0.0f, dposc_f = 0.0f;
    if (tid < G) {
        int g = tid;
        int pfx = sfp[g];
        bool alive = true;
        for (int g2 = g + 1; g2 < G; ++g2)
            if (sfp[g2] == pfx) { alive = false; break; }   // later g wins
        if (alive) {
            int p = pfx;
            float4 pr = reinterpret_cast<const float4*>(priors)[p];
            float px1 = pr.x - pr.z * 0.5f, py1 = pr.y - pr.w * 0.5f;
            float px2 = pr.x + pr.z * 0.5f, py2 = pr.y + pr.w * 0.5f;
            float parea = (px2 - px1) * (py2 - py1);
            float ov = -1.0f; int bidx = 0;
#pragma unroll
            for (int g2 = 0; g2 < G; ++g2) {
                float4 gb = sgt[g2];
                float lx = fmaxf(gb.x, px1), ly = fmaxf(gb.y, py1);
                float rx = fminf(gb.z, px2), ry = fminf(gb.w, py2);
                float w = fmaxf(rx - lx, 0.0f), h = fmaxf(ry - ly, 0.0f);
                float inter = w * h;
                float iou = __fdividef(inter, sga[g2] + parea - inter);
                if (iou > ov) { ov = iou; bidx = g2; }
            }
            bool pos_u = (ov >= POS_TH);
            const float* cv = conf_data + ((size_t)b * P + p) * C;
            float mx = cv[0];
#pragma unroll
            for (int c = 1; c < C; ++c) mx = fmaxf(mx, cv[c]);
            float se = 0.0f;
#pragma unroll
            for (int c = 0; c < C; ++c) se += __expf(cv[c] - mx);
            float lse = mx + __logf(se);
            float4 ld = reinterpret_cast<const float4*>(loc_data)[b * P + p];
            auto boxl = [&](const float4& gb) {
                float mcx = (gb.x + gb.z) * 0.5f, mcy = (gb.y + gb.w) * 0.5f;
                float tx = (mcx - pr.x) / (0.1f * pr.z);
                float ty = (mcy - pr.y) / (0.1f * pr.w);
                float tw = __logf(fmaxf((gb.z - gb.x) / pr.z, 1e-8f)) / 0.2f;
                float th = __logf(fmaxf((gb.w - gb.y) / pr.w, 1e-8f)) / 0.2f;
                return sl1(ld.x - tx) + sl1(ld.y - ty) + sl1(ld.z - tw) + sl1(ld.w - th);
            };
            int cls_f = labels[b * G + g] + 1;
            float lc_f = lse - cv[cls_f];
            float box_f = boxl(sgt[g]);
            float box_u = 0.0f, lc_u = 0.0f;
            if (pos_u) {
                int cls_u = labels[b * G + bidx] + 1;
                lc_u = lse - cv[cls_u];
                box_u = boxl(sgt[bidx]);
            }
            dnp_f   = pos_u ? 0.0f : 1.0f;
            dbox_f  = box_f - box_u;
            dposc_f = lc_f - lc_u;
            mined_mut[(size_t)b * P + p] = 0.0f;   // forced -> pos -> mined 0
        }
    }
    if (wid == 0) {
#pragma unroll
        for (int d = 32; d; d >>= 1) {
            dnp_f   += __shfl_xor(dnp_f, d);
            dbox_f  += __shfl_xor(dbox_f, d);
            dposc_f += __shfl_xor(dposc_f, d);
        }
        if (lane == 0) { scorr[0] = dbox_f; scorr[1] = dposc_f; scorr[2] = dnp_f; }
    }
    __threadfence_block();
    __syncthreads();
    float dboxT = scorr[0], dposcT = scorr[1], dnpT = scorr[2];

    int cnt = 0;
    if (tid < PBM) cnt = (int)partial[b * PBM + tid].z;
#pragma unroll
    for (int d = 32; d; d >>= 1) cnt += __shfl_xor(cnt, d);
    __shared__ int ired[16];
    if (lane == 0) ired[wid] = cnt;
    __syncthreads();
    int np = (int)dnpT;
#pragma unroll
    for (int w2 = 0; w2 < 16; ++w2) np += ired[w2];
    int k = 3 * np; if (k > P - 1) k = P - 1;

    float negval = 0.0f;
    if (k > 0) {
        __shared__ unsigned hist[2048];
        __shared__ unsigned sel[3];
        __shared__ unsigned wtot[16];
        __shared__ unsigned zcs;
        if (tid == 0) { sel[0] = 0u; sel[1] = (unsigned)k; sel[2] = 0u; }
        const int shifts[3] = {21, 10, 0};
        const int widths[3] = {11, 11, 10};
#pragma unroll
        for (int level = 0; level < 3; ++level) {
            int shift = shifts[level];
            unsigned bmask = (1u << widths[level]) - 1u;
            hist[tid] = 0u; hist[tid + 1024] = 0u;
            __syncthreads();
            unsigned pref = sel[0];
            unsigned pmask = level ? (0xFFFFFFFFu << (shift + widths[level])) : 0u;
            unsigned zc = 0;
            for (int i = tid; i < P4; i += 1024) {
                float4 v4 = mb4[i];
                unsigned v;
                v = __float_as_uint(v4.x);
                if (v) { if ((v & pmask) == pref) atomicAdd(&hist[(v >> shift) & bmask], 1u); }
                else ++zc;
                v = __float_as_uint(v4.y);
                if (v) { if ((v & pmask) == pref) atomicAdd(&hist[(v >> shift) & bmask], 1u); }
                else ++zc;
                v = __float_as_uint(v4.z);
                if (v) { if ((v & pmask) == pref) atomicAdd(&hist[(v >> shift) & bmask], 1u); }
                else ++zc;
                v = __float_as_uint(v4.w);
                if (v) { if ((v & pmask) == pref) atomicAdd(&hist[(v >> shift) & bmask], 1u); }
                else ++zc;
            }
            if (level == 0) {
#pragma unroll
                for (int d = 32; d; d >>= 1) zc += __shfl_xor(zc, d);
                if (lane == 0) wtot[wid] = zc;
                __syncthreads();
                if (tid == 0) {
                    unsigned t = 0;
#pragma unroll
                    for (int w2 = 0; w2 < 16; ++w2) t += wtot[w2];
                    zcs = t;
                }
            }
            __syncthreads();
            if (tid == 0 && pref == 0u) hist[0] += zcs;
            __syncthreads();
            unsigned h0 = hist[2 * tid], h1 = hist[2 * tid + 1];
            unsigned x = h0 + h1;
#pragma unroll
            for (int d = 1; d < 64; d <<= 1) {
                unsigned t = __shfl_down(x, d);
                if (lane + d < 64) x += t;
            }
            if (lane == 0) wtot[wid] = x;
            __syncthreads();
            unsigned above = 0;
            for (int w2 = wid + 1; w2 < 16; ++w2) above += wtot[w2];
            unsigned sp = x + above;
            unsigned s2 = sp - h0 - h1;
            unsigned s1 = s2 + h1;
            unsigned want = sel[1];
            __syncthreads();
            if (s1 >= want && s2 < want) {
                sel[0] = pref | (((2u * (unsigned)tid + 1u) & bmask) << shift);
                sel[1] = want - s2;
                sel[2] += s2;
            } else if (sp >= want && s1 < want) {
                sel[0] = pref | (((2u * (unsigned)tid) & bmask) << shift);
                sel[1] = want - s1;
                sel[2] += s1;
            }
            __syncthreads();
        }
        unsigned vk = sel[0];
        unsigned cnt_gt = sel[2];
        float vkf = __uint_as_float(vk);
        float ssum = 0.0f;
        for (int i = tid; i < P4; i += 1024) {
            float4 v4 = mb4[i];
            if (__float_as_uint(v4.x) > vk) ssum += v4.x;
            if (__float_as_uint(v4.y) > vk) ssum += v4.y;
            if (__float_as_uint(v4.z) > vk) ssum += v4.z;
            if (__float_as_uint(v4.w) > vk) ssum += v4.w;
        }
#pragma unroll
        for (int d = 32; d; d >>= 1) ssum += __shfl_xor(ssum, d);
        __shared__ float rs[16];
        if (lane == 0) rs[wid] = ssum;
        __syncthreads();
        if (tid == 0) {
            float tot = 0.0f;
#pragma unroll
            for (int w2 = 0; w2 < 16; ++w2) tot += rs[w2];
            negval = tot + (float)(k - (int)cnt_gt) * vkf;
        }
    }

    __shared__ bool islast;
    if (tid == 0) {
        corr[b] = make_float4(negval, dboxT, dposcT, dnpT);
        __threadfence();
        int old = atomicAdd(done, 1);
        islast = (old == B - 1);
    }
    __syncthreads();
    if (!islast) return;
    __threadfence();

    float sbx = 0.0f, sc = 0.0f, sp2 = 0.0f, sn = 0.0f;
    for (int i = tid; i < B * PBM; i += 1024) {
        float4 v = partial[i];
        sbx += v.x; sc += v.y; sp2 += v.z;
    }
    if (tid < B) {
        float4 cr = corr[tid];
        sn += cr.x; sbx += cr.y; sc += cr.z; sp2 += cr.w;
    }
#pragma unroll
    for (int d = 32; d; d >>= 1) {
        sbx += __shfl_xor(sbx, d);
        sc  += __shfl_xor(sc, d);
        sp2 += __shfl_xor(sp2, d);
        sn  += __shfl_xor(sn, d);
    }
    __shared__ float fr[16][4];
    if (lane == 0) { fr[wid][0] = sbx; fr[wid][1] = sc; fr[wid][2] = sp2; fr[wid][3] = sn; }
    __syncthreads();
    if (tid == 0) {
        float tb = 0, tc = 0, tp = 0, tn = 0;
#pragma unroll
        for (int w2 = 0; w2 < 16; ++w2) {
            tb += fr[w2][0]; tc += fr[w2][1]; tp += fr[w2][2]; tn += fr[w2][3];
        }
        float npos = fmaxf(tp, 1.0f);
        out[0] = tb / npos * 1.5f + (tc + tn) / npos * 6.5f;
    }
}

extern "C" void kernel_launch(void* const* d_in, const int* in_sizes, int n_in,
                              void* d_out, int out_size, void* d_ws, size_t ws_size,
                              hipStream_t stream) {
    const float* loc    = (const float*)d_in[0];
    const float* conf   = (const float*)d_in[1];
    const float* priors = (const float*)d_in[2];
    const float* gt     = (const float*)d_in[3];
    const int*   labels = (const int*)d_in[4];
    float* out = (float*)d_out;

    char* w = (char*)d_ws;
    float4* partial = (float4*)w;                      w += sizeof(float4) * B * PBM;
    float* mined  = (float*)w;                         w += sizeof(float) * B * P;
    unsigned long long* bp_part = (unsigned long long*)w;
    w += sizeof(unsigned long long) * NPART * B * G;
    float4* corr  = (float4*)w;                        w += sizeof(float4) * B;
    int*   done   = (int*)w;                           w += sizeof(int);

    // 2 graph nodes. All workspace fully overwritten each call; done zeroed
    // by block (0,0) of k_mega (node 1).
    k_mega<<<dim3(PBM, B), TM, 0, stream>>>(loc, conf, priors, gt, labels,
                                            bp_part, mined, partial, done);
    k_topk<<<B, 1024, 0, stream>>>(mined, partial, bp_part,
                                   loc, conf, priors, gt, labels,
                                   mined, corr, done, out);
}

// Round 17
// 76.006 us; speedup vs baseline: 1.2797x; 1.2797x over previous
//
#include <hip/hip_runtime.h>

// Problem constants (from reference setup_inputs)
static constexpr int B = 32;
static constexpr int P = 19248;
static constexpr int G = 32;
static constexpr int C = 41;          // num classes
static constexpr float POS_TH = 0.5f;
static constexpr float NEG_TH = 0.4f;

static constexpr int TM = 128;                   // k_main block size
static constexpr int PBM = (P + TM - 1) / TM;    // 151 tiles per batch
static constexpr int NPART = 16;                 // k_match prior partitions
static constexpr int PPART = P / NPART;          // 1203 (exact)
static constexpr int P4 = P / 4;                 // 4812 float4 per batch

__device__ __forceinline__ float sl1(float d) {
    d = fabsf(d);
    return d < 1.0f ? 0.5f * d * d : d - 0.5f;
}

__device__ __forceinline__ unsigned long long umax64(unsigned long long a,
                                                     unsigned long long b) {
    return a > b ? a : b;
}

// ---------------------------------------------------------------------------
// Kernel 1: per (b,g) best prior. Wave-per-4g: each wave owns g = wid*4..+3,
// so each prior's load + point-form + area amortizes over 4 IoUs (was 2),
// and reduce/store tails halve per g-throughput. 512 blocks x 512 thr,
// 0 LDS, ~45 VGPR -> 2 blocks/CU, 8 waves/SIMD. __fdividef: argmax key only
// (benign ties). Packed-u64 wave reduce ((iou_bits<<32)|~p -> higher IoU,
// then smaller p). Plain stores. Block (0,0) zeroes the topk done-counter.
// ---------------------------------------------------------------------------
__global__ __launch_bounds__(512) void k_match(
    const float* __restrict__ priors, const float* __restrict__ gt,
    unsigned long long* __restrict__ bp_part, int* __restrict__ done) {
    int part = blockIdx.x, b = blockIdx.y;
    if (part == 0 && b == 0 && threadIdx.x == 0) *done = 0;
    int lane = threadIdx.x & 63, wid = threadIdx.x >> 6;   // wid 0..7
    int pbase = part * PPART;
    int gbase = wid * 4;

    float4 gb[4]; float ga[4]; float best[4]; int bi[4];
#pragma unroll
    for (int j = 0; j < 4; ++j) {
        gb[j] = reinterpret_cast<const float4*>(gt)[b * G + gbase + j];  // broadcast
        ga[j] = (gb[j].z - gb[j].x) * (gb[j].w - gb[j].y);
        best[j] = -1.0f; bi[j] = 0;
    }

    for (int i = lane; i < PPART; i += 64) {
        int p = pbase + i;
        float4 pr = reinterpret_cast<const float4*>(priors)[p];
        float px1 = pr.x - pr.z * 0.5f, py1 = pr.y - pr.w * 0.5f;
        float px2 = pr.x + pr.z * 0.5f, py2 = pr.y + pr.w * 0.5f;
        float parea = (px2 - px1) * (py2 - py1);
#pragma unroll
        for (int j = 0; j < 4; ++j) {
            float lx = fmaxf(gb[j].x, px1), ly = fmaxf(gb[j].y, py1);
            float rx = fminf(gb[j].z, px2), ry = fminf(gb[j].w, py2);
            float w = fmaxf(rx - lx, 0.0f), h = fmaxf(ry - ly, 0.0f);
            float inter = w * h;
            float iou = __fdividef(inter, ga[j] + parea - inter);
            if (iou > best[j]) { best[j] = iou; bi[j] = p; }  // ascending p: first max
        }
    }
#pragma unroll
    for (int j = 0; j < 4; ++j) {
        // best >= 0 always (iou >= 0): float bits order-preserving
        unsigned long long pk =
            ((unsigned long long)__float_as_uint(best[j]) << 32)
            | (unsigned)(0xFFFFFFFFu - (unsigned)bi[j]);
#pragma unroll
        for (int d = 32; d; d >>= 1) {
            unsigned long long o = __shfl_xor(pk, d);
            if (o > pk) pk = o;
        }
        if (lane == 0) bp_part[(part * B + b) * G + gbase + j] = pk;
    }
}

// ---------------------------------------------------------------------------
// Kernel 2: main streaming kernel with T14 async-STAGE split:
//   prologue (sforce/sg) -> barrier -> ISSUE global_load_lds -> all
//   conf-independent compute (IoU argmax, force check, box loss) ->
//   vmcnt(0) + barrier -> LSE/CE from LDS.
// Plain partial stores, no atomics/fences.
// ---------------------------------------------------------------------------
__global__ __launch_bounds__(TM) void k_main(
    const float* __restrict__ loc_data, const float* __restrict__ conf_data,
    const float* __restrict__ priors, const float* __restrict__ gt,
    const int* __restrict__ labels,
    const unsigned long long* __restrict__ bp_part,
    float* __restrict__ mined, float4* __restrict__ partial) {
    int b = blockIdx.y;
    int p0 = blockIdx.x * TM;
    int tid = threadIdx.x;
    int p = p0 + tid;
    int lane = tid & 63, wid = tid >> 6;
    __shared__ float sconf[TM * C];
    __shared__ int sforce[G];
    __shared__ float4 sg[G];
    __shared__ float sarea[G];

    // ---- prologue: forced priors + gt boxes (tiny; tid<32 only) ----
    if (tid < G) {
        unsigned long long mx = 0ull;
#pragma unroll
        for (int q = 0; q < NPART; ++q) {
            unsigned long long v = bp_part[(q * B + b) * G + tid];
            mx = umax64(mx, v);
        }
        sforce[tid] = (int)(0xFFFFFFFFu - (unsigned)mx);
        float4 g4 = reinterpret_cast<const float4*>(gt)[b * G + tid];
        sg[tid] = g4;
        sarea[tid] = (g4.z - g4.x) * (g4.w - g4.y);
    }
    __syncthreads();            // sg/sforce visible; no staging in flight yet

    // ---- issue conf staging (async direct-to-LDS), DO NOT wait ----
    int valid = min(TM, P - p0);
    size_t gbase = ((size_t)b * P + p0) * C;
    int tot4 = (valid * C) >> 2;          // exact: 128*41 and 48*41 both %4==0
    const float4* g4p = reinterpret_cast<const float4*>(conf_data + gbase);
    float4* s4 = reinterpret_cast<float4*>(sconf);
#if defined(__has_builtin) && __has_builtin(__builtin_amdgcn_global_load_lds)
    typedef const __attribute__((address_space(1))) char* gas1_t;
    typedef __attribute__((address_space(3))) char* las3_t;
#define GL(j) { int i = tid + (j) * TM; if (i < tot4) \
    __builtin_amdgcn_global_load_lds((gas1_t)(g4p + i), (las3_t)(s4 + i), 16, 0, 0); }
    GL(0) GL(1) GL(2) GL(3) GL(4) GL(5) GL(6) GL(7) GL(8) GL(9) GL(10)
#undef GL
#define STAGE_WAIT asm volatile("s_waitcnt vmcnt(0)" ::: "memory")
#else
    float4 r0, r1, r2, r3, r4, r5, r6, r7, r8, r9, r10;
#define LD(j, rj) { int i = tid + (j) * TM; if (i < tot4) rj = g4p[i]; }
    LD(0, r0) LD(1, r1) LD(2, r2) LD(3, r3) LD(4, r4) LD(5, r5)
    LD(6, r6) LD(7, r7) LD(8, r8) LD(9, r9) LD(10, r10)
#undef LD
#define STAGE_WAIT do { \
    int i; \
    i = tid + 0*TM;  if (i < tot4) s4[i] = r0; \
    i = tid + 1*TM;  if (i < tot4) s4[i] = r1; \
    i = tid + 2*TM;  if (i < tot4) s4[i] = r2; \
    i = tid + 3*TM;  if (i < tot4) s4[i] = r3; \
    i = tid + 4*TM;  if (i < tot4) s4[i] = r4; \
    i = tid + 5*TM;  if (i < tot4) s4[i] = r5; \
    i = tid + 6*TM;  if (i < tot4) s4[i] = r6; \
    i = tid + 7*TM;  if (i < tot4) s4[i] = r7; \
    i = tid + 8*TM;  if (i < tot4) s4[i] = r8; \
    i = tid + 9*TM;  if (i < tot4) s4[i] = r9; \
    i = tid + 10*TM; if (i < tot4) s4[i] = r10; \
} while (0)
#endif

    // ---- conf-independent compute (hides staging latency) ----
    float my_box = 0.0f, my_posc = 0.0f; int my_pos = 0;
    bool pos = false, neutral = false;
    int cls = 0;
    if (p < P) {
        float4 pr = reinterpret_cast<const float4*>(priors)[p];
        float px1 = pr.x - pr.z * 0.5f, py1 = pr.y - pr.w * 0.5f;
        float px2 = pr.x + pr.z * 0.5f, py2 = pr.y + pr.w * 0.5f;
        float parea = (px2 - px1) * (py2 - py1);
        float ov = -1.0f; int bidx = 0;
#pragma unroll
        for (int g = 0; g < G; ++g) {
            float4 gb = sg[g];
            float lx = fmaxf(gb.x, px1), ly = fmaxf(gb.y, py1);
            float rx = fminf(gb.z, px2), ry = fminf(gb.w, py2);
            float w = fmaxf(rx - lx, 0.0f), h = fmaxf(ry - ly, 0.0f);
            float inter = w * h;
            float iou = __fdividef(inter, sarea[g] + parea - inter);
            if (iou > ov) { ov = iou; bidx = g; }   // strict > keeps FIRST g
        }
        int fidx = -1;
#pragma unroll
        for (int g = 0; g < G; ++g)
            if (p == sforce[g]) fidx = g;             // ascending g: LAST wins
        int gidx = 0;
        if (fidx >= 0)            { pos = true; gidx = fidx; }
        else if (ov >= POS_TH)    { pos = true; gidx = bidx; }
        else if (ov >= NEG_TH)    { neutral = true; }
        if (pos) {
            cls = labels[b * G + gidx] + 1;
            float4 gb = sg[gidx];
            float mcx = (gb.x + gb.z) * 0.5f, mcy = (gb.y + gb.w) * 0.5f;
            float tx = (mcx - pr.x) / (0.1f * pr.z);
            float ty = (mcy - pr.y) / (0.1f * pr.w);
            float tw = __logf(fmaxf((gb.z - gb.x) / pr.z, 1e-8f)) / 0.2f;
            float th = __logf(fmaxf((gb.w - gb.y) / pr.w, 1e-8f)) / 0.2f;
            float4 ld = reinterpret_cast<const float4*>(loc_data)[b * P + p];
            my_box = sl1(ld.x - tx) + sl1(ld.y - ty) + sl1(ld.z - tw) + sl1(ld.w - th);
        }
        my_pos = pos ? 1 : 0;
    }

    // ---- staging complete -> LSE/CE ----
    STAGE_WAIT;
#undef STAGE_WAIT
    __syncthreads();

    if (p < P) {
        const float* cv = &sconf[tid * C];
        float mx = cv[0];
#pragma unroll
        for (int c = 1; c < C; ++c) mx = fmaxf(mx, cv[c]);
        float se = 0.0f;
#pragma unroll
        for (int c = 0; c < C; ++c) se += __expf(cv[c] - mx);
        float lse = mx + __logf(se);
        float lc = lse - cv[cls];          // >= 0 always (lse >= mx >= picked)
        mined[(size_t)b * P + p] = (pos || neutral) ? 0.0f : lc;
        my_posc = pos ? lc : 0.0f;
    }

#pragma unroll
    for (int d = 32; d; d >>= 1) {
        my_box  += __shfl_xor(my_box, d);
        my_posc += __shfl_xor(my_posc, d);
        my_pos  += __shfl_xor(my_pos, d);
    }
    __shared__ float rb[2], rc[2]; __shared__ int rp[2];
    if (lane == 0) { rb[wid] = my_box; rc[wid] = my_posc; rp[wid] = my_pos; }
    __syncthreads();
    if (tid == 0) {
        partial[b * PBM + blockIdx.x] =
            make_float4(rb[0] + rb[1], rc[0] + rc[1], (float)(rp[0] + rp[1]), 0.0f);
    }
}

// ---------------------------------------------------------------------------
// Kernel 3: per batch, sum of top-k of mined (k = min(3*npos_b, P-1)) via
// 3-level radix select, float4 passes, parallel suffix-scan selection.
// Zero values skip the LDS atomic (ballot-counted once, added to hist[0]
// arithmetically when pref==0). LAST block (done counter, O(32) fences)
// reduces partials + neg_b -> out.
// ---------------------------------------------------------------------------
__global__ __launch_bounds__(1024) void k_topk(
    const float* __restrict__ mined, const float4* __restrict__ partial,
    float* __restrict__ neg_b, int* __restrict__ done,
    float* __restrict__ out) {
    int b = blockIdx.x;
    const float4* mb4 = reinterpret_cast<const float4*>(mined + (size_t)b * P);
    int tid = threadIdx.x;
    int lane = tid & 63, wid = tid >> 6;

    // npos for this batch from partials
    int cnt = 0;
    if (tid < PBM) cnt = (int)partial[b * PBM + tid].z;
#pragma unroll
    for (int d = 32; d; d >>= 1) cnt += __shfl_xor(cnt, d);
    __shared__ int ired[16];
    if (lane == 0) ired[wid] = cnt;
    __syncthreads();
    int np = 0;
#pragma unroll
    for (int w2 = 0; w2 < 16; ++w2) np += ired[w2];
    int k = 3 * np; if (k > P - 1) k = P - 1;

    float negval = 0.0f;                  // valid on tid 0
    if (k > 0) {                          // block-uniform
        __shared__ unsigned hist[2048];
        __shared__ unsigned sel[3];       // [0]=prefix, [1]=want, [2]=cnt_gt
        __shared__ unsigned wtot[16];
        __shared__ unsigned zcs;          // block-wide zero count
        if (tid == 0) { sel[0] = 0u; sel[1] = (unsigned)k; sel[2] = 0u; }
        const int shifts[3] = {21, 10, 0};
        const int widths[3] = {11, 11, 10};
#pragma unroll
        for (int level = 0; level < 3; ++level) {
            int shift = shifts[level];
            unsigned bmask = (1u << widths[level]) - 1u;
            hist[tid] = 0u; hist[tid + 1024] = 0u;
            __syncthreads();
            unsigned pref = sel[0];
            unsigned pmask = level ? (0xFFFFFFFFu << (shift + widths[level])) : 0u;
            unsigned zc = 0;
            for (int i = tid; i < P4; i += 1024) {
                float4 v4 = mb4[i];
                unsigned v;
                v = __float_as_uint(v4.x);
                if (v) { if ((v & pmask) == pref) atomicAdd(&hist[(v >> shift) & bmask], 1u); }
                else ++zc;
                v = __float_as_uint(v4.y);
                if (v) { if ((v & pmask) == pref) atomicAdd(&hist[(v >> shift) & bmask], 1u); }
                else ++zc;
                v = __float_as_uint(v4.z);
                if (v) { if ((v & pmask) == pref) atomicAdd(&hist[(v >> shift) & bmask], 1u); }
                else ++zc;
                v = __float_as_uint(v4.w);
                if (v) { if ((v & pmask) == pref) atomicAdd(&hist[(v >> shift) & bmask], 1u); }
                else ++zc;
            }
            if (level == 0) {             // count zeros once (same every level)
#pragma unroll
                for (int d = 32; d; d >>= 1) zc += __shfl_xor(zc, d);
                if (lane == 0) wtot[wid] = zc;    // reuse wtot as scratch
                __syncthreads();
                if (tid == 0) {
                    unsigned t = 0;
#pragma unroll
                    for (int w2 = 0; w2 < 16; ++w2) t += wtot[w2];
                    zcs = t;
                }
            }
            __syncthreads();
            if (tid == 0 && pref == 0u) hist[0] += zcs;
            __syncthreads();
            // parallel suffix-scan selection: thread owns bins 2t, 2t+1
            unsigned h0 = hist[2 * tid], h1 = hist[2 * tid + 1];
            unsigned x = h0 + h1;
#pragma unroll
            for (int d = 1; d < 64; d <<= 1) {
                unsigned t = __shfl_down(x, d);
                if (lane + d < 64) x += t;
            }
            if (lane == 0) wtot[wid] = x;
            __syncthreads();
            unsigned above = 0;
            for (int w2 = wid + 1; w2 < 16; ++w2) above += wtot[w2];
            unsigned sp = x + above;             // S(2t): suffix from bin 2t
            unsigned s2 = sp - h0 - h1;          // S(2t+2)
            unsigned s1 = s2 + h1;               // S(2t+1)
            unsigned want = sel[1];
            __syncthreads();                     // all read want before writes
            if (s1 >= want && s2 < want) {       // bin 2t+1 crosses
                sel[0] = pref | (((2u * (unsigned)tid + 1u) & bmask) << shift);
                sel[1] = want - s2;
                sel[2] += s2;
            } else if (sp >= want && s1 < want) {// bin 2t crosses
                sel[0] = pref | (((2u * (unsigned)tid) & bmask) << shift);
                sel[1] = want - s1;
                sel[2] += s1;
            }
            __syncthreads();
        }
        unsigned vk = sel[0];
        unsigned cnt_gt = sel[2];
        float vkf = __uint_as_float(vk);
        float ssum = 0.0f;
        for (int i = tid; i < P4; i += 1024) {
            float4 v4 = mb4[i];
            if (__float_as_uint(v4.x) > vk) ssum += v4.x;
            if (__float_as_uint(v4.y) > vk) ssum += v4.y;
            if (__float_as_uint(v4.z) > vk) ssum += v4.z;
            if (__float_as_uint(v4.w) > vk) ssum += v4.w;
        }
#pragma unroll
        for (int d = 32; d; d >>= 1) ssum += __shfl_xor(ssum, d);
        __shared__ float rs[16];
        if (lane == 0) rs[wid] = ssum;
        __syncthreads();
        if (tid == 0) {
            float tot = 0.0f;
#pragma unroll
            for (int w2 = 0; w2 < 16; ++w2) tot += rs[w2];
            negval = tot + (float)(k - (int)cnt_gt) * vkf;
        }
    }

    // completion protocol (O(32) device-scope fences total — proven cheap)
    __shared__ bool islast;
    if (tid == 0) {
        neg_b[b] = negval;
        __threadfence();                       // release neg_b
        int old = atomicAdd(done, 1);
        islast = (old == B - 1);
    }
    __syncthreads();
    if (!islast) return;
    __threadfence();                           // acquire other blocks' neg_b

    float sbx = 0.0f, sc = 0.0f, sp2 = 0.0f, sn = 0.0f;
    for (int i = tid; i < B * PBM; i += 1024) {
        float4 v = partial[i];
        sbx += v.x; sc += v.y; sp2 += v.z;
    }
    if (tid < B) sn = neg_b[tid];
#pragma unroll
    for (int d = 32; d; d >>= 1) {
        sbx += __shfl_xor(sbx, d);
        sc  += __shfl_xor(sc, d);
        sp2 += __shfl_xor(sp2, d);
        sn  += __shfl_xor(sn, d);
    }
    __shared__ float fr[16][4];
    if (lane == 0) { fr[wid][0] = sbx; fr[wid][1] = sc; fr[wid][2] = sp2; fr[wid][3] = sn; }
    __syncthreads();
    if (tid == 0) {
        float tb = 0, tc = 0, tp = 0, tn = 0;
#pragma unroll
        for (int w2 = 0; w2 < 16; ++w2) {
            tb += fr[w2][0]; tc += fr[w2][1]; tp += fr[w2][2]; tn += fr[w2][3];
        }
        float npos = fmaxf(tp, 1.0f);
        out[0] = tb / npos * 1.5f + (tc + tn) / npos * 6.5f;
    }
}

extern "C" void kernel_launch(void* const* d_in, const int* in_sizes, int n_in,
                              void* d_out, int out_size, void* d_ws, size_t ws_size,
                              hipStream_t stream) {
    const float* loc    = (const float*)d_in[0];
    const float* conf   = (const float*)d_in[1];
    const float* priors = (const float*)d_in[2];
    const float* gt     = (const float*)d_in[3];
    const int*   labels = (const int*)d_in[4];
    float* out = (float*)d_out;

    char* w = (char*)d_ws;
    float4* partial = (float4*)w;                      w += sizeof(float4) * B * PBM;
    float* mined  = (float*)w;                         w += sizeof(float) * B * P;
    unsigned long long* bp_part = (unsigned long long*)w;
    w += sizeof(unsigned long long) * NPART * B * G;
    float* negb   = (float*)w;                         w += sizeof(float) * B;
    int*   done   = (int*)w;                           w += sizeof(int);

    // 3 graph nodes. bp_part/partial/mined/negb fully overwritten each call;
    // done zeroed inside k_match (node 1).
    k_match<<<dim3(NPART, B), 512, 0, stream>>>(priors, gt, bp_part, done);
    k_main<<<dim3(PBM, B), TM, 0, stream>>>(loc, conf, priors, gt, labels,
                                            bp_part, mined, partial);
    k_topk<<<B, 1024, 0, stream>>>(mined, partial, negb, done, out);
}